// Round 1
// baseline (1446.429 us; speedup 1.0000x reference)
//
#include <hip/hip_runtime.h>
#include <cstdint>

#define TTOK 8192
#define HID  1024
#define FFD  4096
#define NEXP 8
#define NASSIGN 16384   // TTOK * 2
#define MAXMB 64        // 8192 / 128

typedef __attribute__((ext_vector_type(8))) short bf16x8;
typedef __attribute__((ext_vector_type(4))) float f32x4;

__device__ __forceinline__ unsigned short f2bf(float f) {
  unsigned int u = __builtin_bit_cast(unsigned int, f);
  u += 0x7FFFu + ((u >> 16) & 1u);           // RNE
  return (unsigned short)(u >> 16);
}

__device__ __forceinline__ void gload16(const unsigned short* g, unsigned short* l) {
  __builtin_amdgcn_global_load_lds(
      (const __attribute__((address_space(1))) unsigned int*)g,
      (__attribute__((address_space(3))) unsigned int*)l, 16, 0, 0);
}

// ---------------- routing ----------------

__global__ void zero_counts_kernel(int* counts) {
  if (threadIdx.x < NEXP) counts[threadIdx.x] = 0;
}

__global__ void gate_kernel(const float* __restrict__ x,
                            const float* __restrict__ gw,
                            const float* __restrict__ gb,
                            float* __restrict__ logits_out,
                            int* __restrict__ counts,
                            int* __restrict__ te, int* __restrict__ tp,
                            float* __restrict__ tw) {
  const int lane = threadIdx.x & 63;
  const int wib  = threadIdx.x >> 6;
  const int t = blockIdx.x * 4 + wib;
  const float* xr = x + (size_t)t * HID;

  float acc[NEXP];
#pragma unroll
  for (int e = 0; e < NEXP; ++e) acc[e] = 0.f;

#pragma unroll
  for (int i = 0; i < HID / 64; ++i) {
    int h = lane + 64 * i;
    float xv = xr[h];
    const float* g = gw + h * NEXP;
#pragma unroll
    for (int e = 0; e < NEXP; ++e) acc[e] += xv * g[e];
  }
#pragma unroll
  for (int off = 32; off; off >>= 1)
#pragma unroll
    for (int e = 0; e < NEXP; ++e) acc[e] += __shfl_xor(acc[e], off);
#pragma unroll
  for (int e = 0; e < NEXP; ++e) acc[e] += gb[e];

  if (lane < NEXP) logits_out[(size_t)t * NEXP + lane] = acc[lane];

  if (lane == 0) {
    int e0 = 0; float v0 = acc[0];
#pragma unroll
    for (int e = 1; e < NEXP; ++e) if (acc[e] > v0) { v0 = acc[e]; e0 = e; }
    int e1 = -1; float v1 = -3.4e38f;
#pragma unroll
    for (int e = 0; e < NEXP; ++e) if (e != e0 && acc[e] > v1) { v1 = acc[e]; e1 = e; }
    float s = __expf(v1 - v0);         // v1 <= v0
    float w0 = 1.f / (1.f + s);
    float w1 = s * w0;
    int p0 = atomicAdd(&counts[e0], 1);
    int p1 = atomicAdd(&counts[e1], 1);
    te[t * 2] = e0; te[t * 2 + 1] = e1;
    tp[t * 2] = p0; tp[t * 2 + 1] = p1;
    tw[t * 2] = w0; tw[t * 2 + 1] = w1;
  }
}

__global__ void scatter_kernel(const int* __restrict__ counts, int* __restrict__ offsets,
                               const int* __restrict__ te, const int* __restrict__ tp,
                               const float* __restrict__ tw,
                               int* __restrict__ tok_of, float* __restrict__ wt_of,
                               int* __restrict__ asn_of) {
  __shared__ int offs[NEXP];
  if (threadIdx.x == 0) {
    int run = 0;
    for (int e = 0; e < NEXP; ++e) { offs[e] = run; offsets[e] = run; run += counts[e]; }
  }
  __syncthreads();
  for (int t = threadIdx.x; t < TTOK; t += blockDim.x) {
#pragma unroll
    for (int j = 0; j < 2; ++j) {
      int e = te[t * 2 + j];
      int a = offs[e] + tp[t * 2 + j];
      tok_of[a] = t;
      wt_of[a] = tw[t * 2 + j];
      asn_of[t * 2 + j] = a;
    }
  }
}

// ---------------- dtype prep ----------------

__global__ void convert_x_kernel(const float* __restrict__ x, unsigned short* __restrict__ xb) {
  size_t i = ((size_t)blockIdx.x * 256 + threadIdx.x) * 8;
  float4 a = *(const float4*)(x + i);
  float4 b = *(const float4*)(x + i + 4);
  union { unsigned short us[8]; uint4 v; } u;
  u.us[0] = f2bf(a.x); u.us[1] = f2bf(a.y); u.us[2] = f2bf(a.z); u.us[3] = f2bf(a.w);
  u.us[4] = f2bf(b.x); u.us[5] = f2bf(b.y); u.us[6] = f2bf(b.z); u.us[7] = f2bf(b.w);
  *(uint4*)(xb + i) = u.v;
}

// src [z][R][C] fp32 -> dst [z][C][R] bf16
__global__ void transpose_cvt_kernel(const float* __restrict__ src,
                                     unsigned short* __restrict__ dst, int R, int C) {
  __shared__ float tile[32][33];
  const int r0 = blockIdx.y * 32, c0 = blockIdx.x * 32;
  const size_t base = (size_t)blockIdx.z * R * C;
  src += base; dst += base;
#pragma unroll
  for (int i = threadIdx.y; i < 32; i += 8)
    tile[i][threadIdx.x] = src[(size_t)(r0 + i) * C + c0 + threadIdx.x];
  __syncthreads();
#pragma unroll
  for (int i = threadIdx.y; i < 32; i += 8)
    dst[(size_t)(c0 + i) * R + r0 + threadIdx.x] = f2bf(tile[threadIdx.x][i]);
}

// ---------------- expert GEMMs ----------------
// 128x128 tile, BK=32, 4 waves (2x2), each wave 64x64 via 4x4 frags of 16x16x32.

__global__ __launch_bounds__(256, 2) void moe_up_kernel(
    const unsigned short* __restrict__ xb,    // [T][H] bf16
    const unsigned short* __restrict__ WgT,   // [E][F][H] bf16
    const unsigned short* __restrict__ WuT,   // [E][F][H] bf16
    const int* __restrict__ counts, const int* __restrict__ offsets,
    const int* __restrict__ tok_of,
    unsigned short* __restrict__ hbuf)        // [A][F] bf16
{
  const int e = blockIdx.x >> 6;
  const int mblk = blockIdx.x & 63;
  const int cnt = counts[e];
  if (mblk * 128 >= cnt) return;
  const int off = offsets[e];
  const int n0 = blockIdx.y * 128;

  __shared__ __align__(16) unsigned short As[128 * 32];
  __shared__ __align__(16) unsigned short Bg[128 * 32];
  __shared__ __align__(16) unsigned short Bu[128 * 32];
  __shared__ int toks[128];

  const int tid = threadIdx.x;
  const int lane = tid & 63;
  const int w = tid >> 6;

  if (tid < 128) {
    int a = off + mblk * 128 + tid;
    if (a > NASSIGN - 1) a = NASSIGN - 1;
    toks[tid] = tok_of[a];
  }
  __syncthreads();

  const unsigned short* asrc[2];
  const unsigned short* bgsrc[2];
  const unsigned short* busrc[2];
#pragma unroll
  for (int j = 0; j < 2; ++j) {
    int rrow = w * 32 + j * 16 + (lane >> 2);
    int kcol = 8 * (lane & 3);
    asrc[j]  = xb  + (size_t)toks[rrow] * HID + kcol;
    bgsrc[j] = WgT + ((size_t)e * FFD + n0 + rrow) * HID + kcol;
    busrc[j] = WuT + ((size_t)e * FFD + n0 + rrow) * HID + kcol;
  }

  f32x4 accg[4][4] = {};
  f32x4 accu[4][4] = {};
  const int wr = (w >> 1) * 64, wc = (w & 1) * 64;
  const int lr = lane & 15, kg = (lane >> 4) * 8;

  for (int k0 = 0; k0 < HID; k0 += 32) {
    __syncthreads();
#pragma unroll
    for (int j = 0; j < 2; ++j) {
      gload16(asrc[j]  + k0, &As[w * 1024 + j * 512]);
      gload16(bgsrc[j] + k0, &Bg[w * 1024 + j * 512]);
      gload16(busrc[j] + k0, &Bu[w * 1024 + j * 512]);
    }
    __syncthreads();
    bf16x8 af[4], bgf[4], buf_[4];
#pragma unroll
    for (int m = 0; m < 4; ++m)
      af[m] = *(const bf16x8*)&As[(wr + m * 16 + lr) * 32 + kg];
#pragma unroll
    for (int n = 0; n < 4; ++n) {
      bgf[n]  = *(const bf16x8*)&Bg[(wc + n * 16 + lr) * 32 + kg];
      buf_[n] = *(const bf16x8*)&Bu[(wc + n * 16 + lr) * 32 + kg];
    }
#pragma unroll
    for (int m = 0; m < 4; ++m)
#pragma unroll
      for (int n = 0; n < 4; ++n) {
        accg[m][n] = __builtin_amdgcn_mfma_f32_16x16x32_bf16(af[m], bgf[n],  accg[m][n], 0, 0, 0);
        accu[m][n] = __builtin_amdgcn_mfma_f32_16x16x32_bf16(af[m], buf_[n], accu[m][n], 0, 0, 0);
      }
  }

  const int crb = (lane >> 4) * 4, cc = lane & 15;
#pragma unroll
  for (int m = 0; m < 4; ++m)
#pragma unroll
    for (int n = 0; n < 4; ++n)
#pragma unroll
      for (int r = 0; r < 4; ++r) {
        int lrow = wr + m * 16 + crb + r;
        int grow = mblk * 128 + lrow;
        if (grow < cnt) {
          size_t a = (size_t)off + grow;
          float g = accg[m][n][r];
          float u = accu[m][n][r];
          float sg = g / (1.0f + __expf(-g));   // silu
          hbuf[a * FFD + (n0 + wc + n * 16 + cc)] = f2bf(sg * u);
        }
      }
}

__global__ __launch_bounds__(256, 2) void moe_down_kernel(
    const unsigned short* __restrict__ hb,    // [A][F] bf16
    const unsigned short* __restrict__ WdT,   // [E][H][F] bf16
    const int* __restrict__ counts, const int* __restrict__ offsets,
    float* __restrict__ ypart)                // [A][H] fp32
{
  const int e = blockIdx.x >> 6;
  const int mblk = blockIdx.x & 63;
  const int cnt = counts[e];
  if (mblk * 128 >= cnt) return;
  const int off = offsets[e];
  const int n0 = blockIdx.y * 128;

  __shared__ __align__(16) unsigned short As[128 * 32];
  __shared__ __align__(16) unsigned short Bs[128 * 32];

  const int tid = threadIdx.x;
  const int lane = tid & 63;
  const int w = tid >> 6;

  const unsigned short* asrc[2];
  const unsigned short* bsrc[2];
#pragma unroll
  for (int j = 0; j < 2; ++j) {
    int rrow = w * 32 + j * 16 + (lane >> 2);
    int kcol = 8 * (lane & 3);
    int a = off + mblk * 128 + rrow;
    if (a > NASSIGN - 1) a = NASSIGN - 1;
    asrc[j] = hb + (size_t)a * FFD + kcol;
    bsrc[j] = WdT + ((size_t)e * HID + n0 + rrow) * FFD + kcol;
  }

  f32x4 acc[4][4] = {};
  const int wr = (w >> 1) * 64, wc = (w & 1) * 64;
  const int lr = lane & 15, kg = (lane >> 4) * 8;

  for (int k0 = 0; k0 < FFD; k0 += 32) {
    __syncthreads();
#pragma unroll
    for (int j = 0; j < 2; ++j) {
      gload16(asrc[j] + k0, &As[w * 1024 + j * 512]);
      gload16(bsrc[j] + k0, &Bs[w * 1024 + j * 512]);
    }
    __syncthreads();
    bf16x8 af[4], bf_[4];
#pragma unroll
    for (int m = 0; m < 4; ++m)
      af[m] = *(const bf16x8*)&As[(wr + m * 16 + lr) * 32 + kg];
#pragma unroll
    for (int n = 0; n < 4; ++n)
      bf_[n] = *(const bf16x8*)&Bs[(wc + n * 16 + lr) * 32 + kg];
#pragma unroll
    for (int m = 0; m < 4; ++m)
#pragma unroll
      for (int n = 0; n < 4; ++n)
        acc[m][n] = __builtin_amdgcn_mfma_f32_16x16x32_bf16(af[m], bf_[n], acc[m][n], 0, 0, 0);
  }

  const int crb = (lane >> 4) * 4, cc = lane & 15;
#pragma unroll
  for (int m = 0; m < 4; ++m)
#pragma unroll
    for (int n = 0; n < 4; ++n)
#pragma unroll
      for (int r = 0; r < 4; ++r) {
        int lrow = wr + m * 16 + crb + r;
        int grow = mblk * 128 + lrow;
        if (grow < cnt)
          ypart[((size_t)off + grow) * HID + (n0 + wc + n * 16 + cc)] = acc[m][n][r];
      }
}

__global__ void combine_kernel(const float* __restrict__ ypart,
                               const int* __restrict__ asn_of,
                               const float* __restrict__ wt_of,
                               float* __restrict__ y) {
  const int t = blockIdx.x;
  const int a0 = asn_of[t * 2], a1 = asn_of[t * 2 + 1];
  const float w0 = wt_of[a0], w1 = wt_of[a1];
  const int c = threadIdx.x * 4;
  float4 p0 = *(const float4*)&ypart[(size_t)a0 * HID + c];
  float4 p1 = *(const float4*)&ypart[(size_t)a1 * HID + c];
  float4 r;
  r.x = w0 * p0.x + w1 * p1.x;
  r.y = w0 * p0.y + w1 * p1.y;
  r.z = w0 * p0.z + w1 * p1.z;
  r.w = w0 * p0.w + w1 * p1.w;
  *(float4*)&y[(size_t)t * HID + c] = r;
}

// ---------------- launch ----------------

extern "C" void kernel_launch(void* const* d_in, const int* in_sizes, int n_in,
                              void* d_out, int out_size, void* d_ws, size_t ws_size,
                              hipStream_t stream) {
  const float* x  = (const float*)d_in[0];
  const float* gw = (const float*)d_in[1];
  const float* gb = (const float*)d_in[2];
  const float* Wg = (const float*)d_in[3];
  const float* Wu = (const float*)d_in[4];
  const float* Wd = (const float*)d_in[5];
  float* out = (float*)d_out;
  float* logits = out + (size_t)TTOK * HID;

  char* ws = (char*)d_ws;
  size_t o = 0;
  auto carve = [&](size_t b) { char* p = ws + o; o += (b + 255) & ~(size_t)255; return p; };
  int*   counts  = (int*)carve(NEXP * 4);
  int*   offsets = (int*)carve(NEXP * 4);
  int*   te      = (int*)carve((size_t)TTOK * 2 * 4);
  int*   tp      = (int*)carve((size_t)TTOK * 2 * 4);
  float* tw      = (float*)carve((size_t)TTOK * 2 * 4);
  int*   tok_of  = (int*)carve((size_t)NASSIGN * 4);
  float* wt_of   = (float*)carve((size_t)NASSIGN * 4);
  int*   asn_of  = (int*)carve((size_t)TTOK * 2 * 4);
  unsigned short* xb  = (unsigned short*)carve((size_t)TTOK * HID * 2);
  unsigned short* WgT = (unsigned short*)carve((size_t)NEXP * FFD * HID * 2);
  unsigned short* WuT = (unsigned short*)carve((size_t)NEXP * FFD * HID * 2);
  unsigned short* WdT = (unsigned short*)carve((size_t)NEXP * HID * FFD * 2);
  unsigned short* hb  = (unsigned short*)carve((size_t)NASSIGN * FFD * 2);
  float* ypart        = (float*)carve((size_t)NASSIGN * HID * 4);
  (void)ws_size; (void)in_sizes; (void)n_in; (void)out_size;

  zero_counts_kernel<<<dim3(1), dim3(64), 0, stream>>>(counts);
  gate_kernel<<<dim3(TTOK / 4), dim3(256), 0, stream>>>(x, gw, gb, logits, counts, te, tp, tw);
  scatter_kernel<<<dim3(1), dim3(256), 0, stream>>>(counts, offsets, te, tp, tw, tok_of, wt_of, asn_of);
  convert_x_kernel<<<dim3((TTOK * HID) / 2048), dim3(256), 0, stream>>>(x, xb);
  transpose_cvt_kernel<<<dim3(FFD / 32, HID / 32, NEXP), dim3(32, 8), 0, stream>>>(Wg, WgT, HID, FFD);
  transpose_cvt_kernel<<<dim3(FFD / 32, HID / 32, NEXP), dim3(32, 8), 0, stream>>>(Wu, WuT, HID, FFD);
  transpose_cvt_kernel<<<dim3(HID / 32, FFD / 32, NEXP), dim3(32, 8), 0, stream>>>(Wd, WdT, FFD, HID);
  moe_up_kernel<<<dim3(NEXP * MAXMB, FFD / 128), dim3(256), 0, stream>>>(xb, WgT, WuT, counts, offsets, tok_of, hb);
  moe_down_kernel<<<dim3(NEXP * MAXMB, HID / 128), dim3(256), 0, stream>>>(hb, WdT, counts, offsets, ypart);
  combine_kernel<<<dim3(TTOK), dim3(256), 0, stream>>>(ypart, asn_of, wt_of, out);
}

// Round 2
// 1044.210 us; speedup vs baseline: 1.3852x; 1.3852x over previous
//
#include <hip/hip_runtime.h>
#include <cstdint>

#define TTOK 8192
#define HID  1024
#define FFD  4096
#define NEXP 8
#define NASSIGN 16384   // TTOK * 2
#define MAXMB 64        // 8192 / 128

typedef __attribute__((ext_vector_type(8))) short bf16x8;
typedef __attribute__((ext_vector_type(4))) float f32x4;

__device__ __forceinline__ unsigned short f2bf(float f) {
  unsigned int u = __builtin_bit_cast(unsigned int, f);
  u += 0x7FFFu + ((u >> 16) & 1u);           // RNE
  return (unsigned short)(u >> 16);
}

__device__ __forceinline__ void gload16(const unsigned short* g, unsigned short* l) {
  __builtin_amdgcn_global_load_lds(
      (const __attribute__((address_space(1))) unsigned int*)g,
      (__attribute__((address_space(3))) unsigned int*)l, 16, 0, 0);
}

// ---------------- routing ----------------

__global__ void zero_counts_kernel(int* counts) {
  if (threadIdx.x < NEXP) counts[threadIdx.x] = 0;
}

__global__ void gate_kernel(const float* __restrict__ x,
                            const float* __restrict__ gw,
                            const float* __restrict__ gb,
                            float* __restrict__ logits_out,
                            int* __restrict__ counts,
                            int* __restrict__ te, int* __restrict__ tp,
                            float* __restrict__ tw) {
  const int lane = threadIdx.x & 63;
  const int wib  = threadIdx.x >> 6;
  const int t = blockIdx.x * 4 + wib;
  const float* xr = x + (size_t)t * HID;

  float acc[NEXP];
#pragma unroll
  for (int e = 0; e < NEXP; ++e) acc[e] = 0.f;

#pragma unroll
  for (int i = 0; i < HID / 64; ++i) {
    int h = lane + 64 * i;
    float xv = xr[h];
    const float* g = gw + h * NEXP;
#pragma unroll
    for (int e = 0; e < NEXP; ++e) acc[e] += xv * g[e];
  }
#pragma unroll
  for (int off = 32; off; off >>= 1)
#pragma unroll
    for (int e = 0; e < NEXP; ++e) acc[e] += __shfl_xor(acc[e], off);
#pragma unroll
  for (int e = 0; e < NEXP; ++e) acc[e] += gb[e];

  if (lane < NEXP) logits_out[(size_t)t * NEXP + lane] = acc[lane];

  if (lane == 0) {
    int e0 = 0; float v0 = acc[0];
#pragma unroll
    for (int e = 1; e < NEXP; ++e) if (acc[e] > v0) { v0 = acc[e]; e0 = e; }
    int e1 = -1; float v1 = -3.4e38f;
#pragma unroll
    for (int e = 0; e < NEXP; ++e) if (e != e0 && acc[e] > v1) { v1 = acc[e]; e1 = e; }
    float s = __expf(v1 - v0);         // v1 <= v0
    float w0 = 1.f / (1.f + s);
    float w1 = s * w0;
    int p0 = atomicAdd(&counts[e0], 1);
    int p1 = atomicAdd(&counts[e1], 1);
    te[t * 2] = e0; te[t * 2 + 1] = e1;
    tp[t * 2] = p0; tp[t * 2 + 1] = p1;
    tw[t * 2] = w0; tw[t * 2 + 1] = w1;
  }
}

__global__ void scatter_kernel(const int* __restrict__ counts, int* __restrict__ offsets,
                               const int* __restrict__ te, const int* __restrict__ tp,
                               const float* __restrict__ tw,
                               int* __restrict__ tok_of, float* __restrict__ wt_of,
                               int* __restrict__ asn_of) {
  __shared__ int offs[NEXP];
  if (threadIdx.x == 0) {
    int run = 0;
    for (int e = 0; e < NEXP; ++e) { offs[e] = run; offsets[e] = run; run += counts[e]; }
  }
  __syncthreads();
  for (int t = threadIdx.x; t < TTOK; t += blockDim.x) {
#pragma unroll
    for (int j = 0; j < 2; ++j) {
      int e = te[t * 2 + j];
      int a = offs[e] + tp[t * 2 + j];
      tok_of[a] = t;
      wt_of[a] = tw[t * 2 + j];
      asn_of[t * 2 + j] = a;
    }
  }
}

// ---------------- dtype prep ----------------

__global__ void convert_x_kernel(const float* __restrict__ x, unsigned short* __restrict__ xb) {
  size_t i = ((size_t)blockIdx.x * 256 + threadIdx.x) * 8;
  float4 a = *(const float4*)(x + i);
  float4 b = *(const float4*)(x + i + 4);
  union { unsigned short us[8]; uint4 v; } u;
  u.us[0] = f2bf(a.x); u.us[1] = f2bf(a.y); u.us[2] = f2bf(a.z); u.us[3] = f2bf(a.w);
  u.us[4] = f2bf(b.x); u.us[5] = f2bf(b.y); u.us[6] = f2bf(b.z); u.us[7] = f2bf(b.w);
  *(uint4*)(xb + i) = u.v;
}

// src [z][R][C] fp32 -> dst [z][C][R] bf16
__global__ void transpose_cvt_kernel(const float* __restrict__ src,
                                     unsigned short* __restrict__ dst, int R, int C) {
  __shared__ float tile[32][33];
  const int r0 = blockIdx.y * 32, c0 = blockIdx.x * 32;
  const size_t base = (size_t)blockIdx.z * R * C;
  src += base; dst += base;
#pragma unroll
  for (int i = threadIdx.y; i < 32; i += 8)
    tile[i][threadIdx.x] = src[(size_t)(r0 + i) * C + c0 + threadIdx.x];
  __syncthreads();
#pragma unroll
  for (int i = threadIdx.y; i < 32; i += 8)
    dst[(size_t)(c0 + i) * R + r0 + threadIdx.x] = f2bf(tile[threadIdx.x][i]);
}

// ---------------- expert GEMMs ----------------
// 128x128 tile, BK=32, 4 waves (2x2), each wave 64x64 via 4x4 frags of 16x16x32.
// Double-buffered LDS, 2-phase pipeline with counted vmcnt (T3 minimum recipe).

__global__ __launch_bounds__(256, 2) void moe_up_kernel(
    const unsigned short* __restrict__ xb,    // [T][H] bf16
    const unsigned short* __restrict__ WgT,   // [E][F][H] bf16
    const unsigned short* __restrict__ WuT,   // [E][F][H] bf16
    const int* __restrict__ counts, const int* __restrict__ offsets,
    const int* __restrict__ tok_of,
    unsigned short* __restrict__ hbuf)        // [A][F] bf16
{
  const int e = blockIdx.x & 7;
  const int mblk = blockIdx.x >> 3;
  const int cnt = counts[e];
  if (mblk * 128 >= cnt) return;
  const int off = offsets[e];
  const int n0 = blockIdx.y * 128;

  __shared__ __align__(16) unsigned short As[2][128 * 32];
  __shared__ __align__(16) unsigned short Bgs[2][128 * 32];
  __shared__ __align__(16) unsigned short Bus[2][128 * 32];
  __shared__ int toks[128];

  const int tid = threadIdx.x;
  const int lane = tid & 63;
  const int w = tid >> 6;

  if (tid < 128) {
    int a = off + mblk * 128 + tid;
    if (a > NASSIGN - 1) a = NASSIGN - 1;
    toks[tid] = tok_of[a];
  }
  __syncthreads();

  const unsigned short* asrc[2];
  const unsigned short* bgsrc[2];
  const unsigned short* busrc[2];
#pragma unroll
  for (int j = 0; j < 2; ++j) {
    int rrow = w * 32 + j * 16 + (lane >> 2);
    int kcol = 8 * (lane & 3);
    asrc[j]  = xb  + (size_t)toks[rrow] * HID + kcol;
    bgsrc[j] = WgT + ((size_t)e * FFD + n0 + rrow) * HID + kcol;
    busrc[j] = WuT + ((size_t)e * FFD + n0 + rrow) * HID + kcol;
  }

  auto STAGE = [&](int buf, int k0) {
#pragma unroll
    for (int j = 0; j < 2; ++j) {
      gload16(asrc[j]  + k0, &As[buf][w * 1024 + j * 512]);
      gload16(bgsrc[j] + k0, &Bgs[buf][w * 1024 + j * 512]);
      gload16(busrc[j] + k0, &Bus[buf][w * 1024 + j * 512]);
    }
  };

  f32x4 accg[4][4] = {};
  f32x4 accu[4][4] = {};
  const int wr = (w >> 1) * 64, wc = (w & 1) * 64;
  const int lr = lane & 15, kg = (lane >> 4) * 8;

  STAGE(0, 0);                                 // prologue: 6 loads in flight
#pragma unroll 1
  for (int t = 0; t < HID / 32; ++t) {
    const int cur = t & 1;
    if (t + 1 < HID / 32) {
      STAGE(cur ^ 1, (t + 1) * 32);            // issue next tile (6 more loads)
      asm volatile("s_waitcnt vmcnt(6)" ::: "memory");   // tile t's 6 loads done
    } else {
      asm volatile("s_waitcnt vmcnt(0)" ::: "memory");
    }
    __builtin_amdgcn_s_barrier();              // buf[cur] ready for all waves

    bf16x8 af[4], bgf[4], buf_[4];
#pragma unroll
    for (int m = 0; m < 4; ++m)
      af[m] = *(const bf16x8*)&As[cur][(wr + m * 16 + lr) * 32 + kg];
#pragma unroll
    for (int n = 0; n < 4; ++n) {
      bgf[n]  = *(const bf16x8*)&Bgs[cur][(wc + n * 16 + lr) * 32 + kg];
      buf_[n] = *(const bf16x8*)&Bus[cur][(wc + n * 16 + lr) * 32 + kg];
    }
#pragma unroll
    for (int m = 0; m < 4; ++m)
#pragma unroll
      for (int n = 0; n < 4; ++n) {
        accg[m][n] = __builtin_amdgcn_mfma_f32_16x16x32_bf16(af[m], bgf[n],  accg[m][n], 0, 0, 0);
        accu[m][n] = __builtin_amdgcn_mfma_f32_16x16x32_bf16(af[m], buf_[n], accu[m][n], 0, 0, 0);
      }
    __builtin_amdgcn_s_barrier();              // reads of buf[cur] done before overwrite
  }

  const int crb = (lane >> 4) * 4, cc = lane & 15;
#pragma unroll
  for (int m = 0; m < 4; ++m)
#pragma unroll
    for (int n = 0; n < 4; ++n)
#pragma unroll
      for (int r = 0; r < 4; ++r) {
        int lrow = wr + m * 16 + crb + r;
        int grow = mblk * 128 + lrow;
        if (grow < cnt) {
          size_t a = (size_t)off + grow;
          float g = accg[m][n][r];
          float u = accu[m][n][r];
          float sg = g / (1.0f + __expf(-g));   // silu
          hbuf[a * FFD + (n0 + wc + n * 16 + cc)] = f2bf(sg * u);
        }
      }
}

__global__ __launch_bounds__(256, 2) void moe_down_kernel(
    const unsigned short* __restrict__ hb,    // [A][F] bf16
    const unsigned short* __restrict__ WdT,   // [E][H][F] bf16
    const int* __restrict__ counts, const int* __restrict__ offsets,
    float* __restrict__ ypart)                // [A][H] fp32
{
  const int e = blockIdx.x & 7;
  const int mblk = blockIdx.x >> 3;
  const int cnt = counts[e];
  if (mblk * 128 >= cnt) return;
  const int off = offsets[e];
  const int n0 = blockIdx.y * 128;

  __shared__ __align__(16) unsigned short As[2][128 * 32];
  __shared__ __align__(16) unsigned short Bs[2][128 * 32];

  const int tid = threadIdx.x;
  const int lane = tid & 63;
  const int w = tid >> 6;

  const unsigned short* asrc[2];
  const unsigned short* bsrc[2];
#pragma unroll
  for (int j = 0; j < 2; ++j) {
    int rrow = w * 32 + j * 16 + (lane >> 2);
    int kcol = 8 * (lane & 3);
    int a = off + mblk * 128 + rrow;
    if (a > NASSIGN - 1) a = NASSIGN - 1;
    asrc[j] = hb + (size_t)a * FFD + kcol;
    bsrc[j] = WdT + ((size_t)e * HID + n0 + rrow) * FFD + kcol;
  }

  auto STAGE = [&](int buf, int k0) {
#pragma unroll
    for (int j = 0; j < 2; ++j) {
      gload16(asrc[j] + k0, &As[buf][w * 1024 + j * 512]);
      gload16(bsrc[j] + k0, &Bs[buf][w * 1024 + j * 512]);
    }
  };

  f32x4 acc[4][4] = {};
  const int wr = (w >> 1) * 64, wc = (w & 1) * 64;
  const int lr = lane & 15, kg = (lane >> 4) * 8;

  STAGE(0, 0);                                 // prologue: 4 loads in flight
#pragma unroll 1
  for (int t = 0; t < FFD / 32; ++t) {
    const int cur = t & 1;
    if (t + 1 < FFD / 32) {
      STAGE(cur ^ 1, (t + 1) * 32);            // +4 loads
      asm volatile("s_waitcnt vmcnt(4)" ::: "memory");   // tile t's 4 loads done
    } else {
      asm volatile("s_waitcnt vmcnt(0)" ::: "memory");
    }
    __builtin_amdgcn_s_barrier();

    bf16x8 af[4], bf_[4];
#pragma unroll
    for (int m = 0; m < 4; ++m)
      af[m] = *(const bf16x8*)&As[cur][(wr + m * 16 + lr) * 32 + kg];
#pragma unroll
    for (int n = 0; n < 4; ++n)
      bf_[n] = *(const bf16x8*)&Bs[cur][(wc + n * 16 + lr) * 32 + kg];
#pragma unroll
    for (int m = 0; m < 4; ++m)
#pragma unroll
      for (int n = 0; n < 4; ++n)
        acc[m][n] = __builtin_amdgcn_mfma_f32_16x16x32_bf16(af[m], bf_[n], acc[m][n], 0, 0, 0);
    __builtin_amdgcn_s_barrier();
  }

  const int crb = (lane >> 4) * 4, cc = lane & 15;
#pragma unroll
  for (int m = 0; m < 4; ++m)
#pragma unroll
    for (int n = 0; n < 4; ++n)
#pragma unroll
      for (int r = 0; r < 4; ++r) {
        int lrow = wr + m * 16 + crb + r;
        int grow = mblk * 128 + lrow;
        if (grow < cnt)
          ypart[((size_t)off + grow) * HID + (n0 + wc + n * 16 + cc)] = acc[m][n][r];
      }
}

__global__ void combine_kernel(const float* __restrict__ ypart,
                               const int* __restrict__ asn_of,
                               const float* __restrict__ wt_of,
                               float* __restrict__ y) {
  const int t = blockIdx.x;
  const int a0 = asn_of[t * 2], a1 = asn_of[t * 2 + 1];
  const float w0 = wt_of[a0], w1 = wt_of[a1];
  const int c = threadIdx.x * 4;
  float4 p0 = *(const float4*)&ypart[(size_t)a0 * HID + c];
  float4 p1 = *(const float4*)&ypart[(size_t)a1 * HID + c];
  float4 r;
  r.x = w0 * p0.x + w1 * p1.x;
  r.y = w0 * p0.y + w1 * p1.y;
  r.z = w0 * p0.z + w1 * p1.z;
  r.w = w0 * p0.w + w1 * p1.w;
  *(float4*)&y[(size_t)t * HID + c] = r;
}

// ---------------- launch ----------------

extern "C" void kernel_launch(void* const* d_in, const int* in_sizes, int n_in,
                              void* d_out, int out_size, void* d_ws, size_t ws_size,
                              hipStream_t stream) {
  const float* x  = (const float*)d_in[0];
  const float* gw = (const float*)d_in[1];
  const float* gb = (const float*)d_in[2];
  const float* Wg = (const float*)d_in[3];
  const float* Wu = (const float*)d_in[4];
  const float* Wd = (const float*)d_in[5];
  float* out = (float*)d_out;
  float* logits = out + (size_t)TTOK * HID;

  char* ws = (char*)d_ws;
  size_t o = 0;
  auto carve = [&](size_t b) { char* p = ws + o; o += (b + 255) & ~(size_t)255; return p; };
  int*   counts  = (int*)carve(NEXP * 4);
  int*   offsets = (int*)carve(NEXP * 4);
  int*   te      = (int*)carve((size_t)TTOK * 2 * 4);
  int*   tp      = (int*)carve((size_t)TTOK * 2 * 4);
  float* tw      = (float*)carve((size_t)TTOK * 2 * 4);
  int*   tok_of  = (int*)carve((size_t)NASSIGN * 4);
  float* wt_of   = (float*)carve((size_t)NASSIGN * 4);
  int*   asn_of  = (int*)carve((size_t)TTOK * 2 * 4);
  unsigned short* xb  = (unsigned short*)carve((size_t)TTOK * HID * 2);
  unsigned short* WgT = (unsigned short*)carve((size_t)NEXP * FFD * HID * 2);
  unsigned short* WuT = (unsigned short*)carve((size_t)NEXP * FFD * HID * 2);
  unsigned short* WdT = (unsigned short*)carve((size_t)NEXP * HID * FFD * 2);
  unsigned short* hb  = (unsigned short*)carve((size_t)NASSIGN * FFD * 2);
  float* ypart        = (float*)carve((size_t)NASSIGN * HID * 4);
  (void)ws_size; (void)in_sizes; (void)n_in; (void)out_size;

  zero_counts_kernel<<<dim3(1), dim3(64), 0, stream>>>(counts);
  gate_kernel<<<dim3(TTOK / 4), dim3(256), 0, stream>>>(x, gw, gb, logits, counts, te, tp, tw);
  scatter_kernel<<<dim3(1), dim3(256), 0, stream>>>(counts, offsets, te, tp, tw, tok_of, wt_of, asn_of);
  convert_x_kernel<<<dim3((TTOK * HID) / 2048), dim3(256), 0, stream>>>(x, xb);
  transpose_cvt_kernel<<<dim3(FFD / 32, HID / 32, NEXP), dim3(32, 8), 0, stream>>>(Wg, WgT, HID, FFD);
  transpose_cvt_kernel<<<dim3(FFD / 32, HID / 32, NEXP), dim3(32, 8), 0, stream>>>(Wu, WuT, HID, FFD);
  transpose_cvt_kernel<<<dim3(HID / 32, FFD / 32, NEXP), dim3(32, 8), 0, stream>>>(Wd, WdT, FFD, HID);
  moe_up_kernel<<<dim3(NEXP * MAXMB, FFD / 128), dim3(256), 0, stream>>>(xb, WgT, WuT, counts, offsets, tok_of, hb);
  moe_down_kernel<<<dim3(NEXP * MAXMB, HID / 128), dim3(256), 0, stream>>>(hb, WdT, counts, offsets, ypart);
  combine_kernel<<<dim3(TTOK), dim3(256), 0, stream>>>(ypart, asn_of, wt_of, out);
}